// Round 1
// baseline (447.877 us; speedup 1.0000x reference)
//
#include <hip/hip_runtime.h>
#include <hip/hip_bf16.h>
#include <math.h>

#define C_CH 8
#define H_DIM 512
#define BS 32768            // B*S = 32*1024 rows
#define K_DIM 4096          // C*H
#define EPS 1e-5f

#define TM 128
#define TN 256
#define TK 32

typedef __bf16 bf16x8 __attribute__((ext_vector_type(8)));
typedef float  floatx4 __attribute__((ext_vector_type(4)));

__device__ __forceinline__ float gelu_exact(float v) {
    return 0.5f * v * (1.0f + erff(v * 0.70710678118654752f));
}

// Fused: (analytic per-channel LN of x*w+b) -> gelu -> GEMM with mod_w^T -> +mod_b
// Writes pre-LN y (fp32) to out. out is [BS, 512].
__global__ __launch_bounds__(512) void fused_gemm_kernel(
    const float* __restrict__ x,
    const float* __restrict__ enc_w,
    const float* __restrict__ enc_b,
    const float* __restrict__ enc_gamma,
    const float* __restrict__ enc_beta,
    const float* __restrict__ mod_w,
    const float* __restrict__ mod_b,
    float* __restrict__ out)
{
    __shared__ float stats[C_CH][5];           // mw, mb, vw, vb, cwb
    __shared__ float pS[C_CH][TM];
    __shared__ float qS[C_CH][TM];
    __shared__ float rS[C_CH][TM];
    __shared__ __align__(16) __bf16 Als[TM][40];   // A tile [m][k], pad 32->40
    __shared__ __align__(16) __bf16 Bls[TN][40];   // B tile [n][k], pad 32->40

    const int tid  = threadIdx.x;
    const int wave = tid >> 6;
    const int lane = tid & 63;

    // ---- per-channel encoder stats (8 waves <-> 8 channels, redundant per block) ----
    {
        const int c = wave;
        float sw = 0.f, sb = 0.f, sww = 0.f, sbb = 0.f, swb = 0.f;
        for (int j = lane; j < H_DIM; j += 64) {
            float w = enc_w[c * H_DIM + j];
            float b = enc_b[c * H_DIM + j];
            sw += w; sb += b;
            sww = fmaf(w, w, sww);
            sbb = fmaf(b, b, sbb);
            swb = fmaf(w, b, swb);
        }
        #pragma unroll
        for (int off = 32; off; off >>= 1) {
            sw  += __shfl_xor(sw,  off);
            sb  += __shfl_xor(sb,  off);
            sww += __shfl_xor(sww, off);
            sbb += __shfl_xor(sbb, off);
            swb += __shfl_xor(swb, off);
        }
        if (lane == 0) {
            const float inv = 1.0f / (float)H_DIM;
            float mw = sw * inv, mb = sb * inv;
            stats[c][0] = mw;
            stats[c][1] = mb;
            stats[c][2] = sww * inv - mw * mw;   // var(w)
            stats[c][3] = sbb * inv - mb * mb;   // var(b)
            stats[c][4] = swb * inv - mw * mb;   // cov(w,b)
        }
    }
    __syncthreads();

    // ---- per-(channel,row) p,q,r ----
    const int row0 = blockIdx.x * TM;
    for (int idx = tid; idx < C_CH * TM; idx += 512) {
        int c = idx >> 7;            // / TM (TM==128)
        int m = idx & (TM - 1);
        float xv = x[c * BS + row0 + m];
        float mw = stats[c][0], mb = stats[c][1];
        float vw = stats[c][2], vb = stats[c][3], cwb = stats[c][4];
        float var = fmaf(xv, fmaf(xv, vw, 2.0f * cwb), vb);
        float q = rsqrtf(var + EPS);
        float p = xv * q;
        pS[c][m] = p;
        qS[c][m] = q;
        rS[c][m] = -fmaf(p, mw, q * mb);
    }
    __syncthreads();

    const int n0b = blockIdx.y * TN;
    const int wm = wave >> 2;        // 0..1
    const int wn = wave & 3;         // 0..3
    const int lr = lane & 15;
    const int lq = lane >> 4;

    floatx4 acc[4][4];
    #pragma unroll
    for (int i = 0; i < 4; ++i)
        #pragma unroll
        for (int j = 0; j < 4; ++j)
            acc[i][j] = (floatx4){0.f, 0.f, 0.f, 0.f};

    // staging assignments
    const int am  = tid >> 2;          // A: row 0..127
    const int akb = (tid & 3) * 8;     // A: k offset 0,8,16,24
    const int bn  = tid >> 1;          // B: n 0..255
    const int bkh = (tid & 1) * 16;    // B: k offset 0 or 16

    for (int kt = 0; kt < K_DIM / TK; ++kt) {
        const int k0 = kt * TK;
        const int c  = k0 >> 9;              // channel of this K-tile
        const int jb = k0 & (H_DIM - 1);     // j base within channel

        // ---- stage A (compute G on the fly) ----
        {
            const int j0 = c * H_DIM + jb + akb;
            float4 w0 = *(const float4*)(enc_w + j0);
            float4 w1 = *(const float4*)(enc_w + j0 + 4);
            float4 b0 = *(const float4*)(enc_b + j0);
            float4 b1 = *(const float4*)(enc_b + j0 + 4);
            float4 g0 = *(const float4*)(enc_gamma + j0);
            float4 g1 = *(const float4*)(enc_gamma + j0 + 4);
            float4 e0 = *(const float4*)(enc_beta + j0);
            float4 e1 = *(const float4*)(enc_beta + j0 + 4);
            float p = pS[c][am], q = qS[c][am], r = rS[c][am];
            float fw[8] = {w0.x, w0.y, w0.z, w0.w, w1.x, w1.y, w1.z, w1.w};
            float fb[8] = {b0.x, b0.y, b0.z, b0.w, b1.x, b1.y, b1.z, b1.w};
            float fg[8] = {g0.x, g0.y, g0.z, g0.w, g1.x, g1.y, g1.z, g1.w};
            float fe[8] = {e0.x, e0.y, e0.z, e0.w, e1.x, e1.y, e1.z, e1.w};
            bf16x8 hv;
            #pragma unroll
            for (int i = 0; i < 8; ++i) {
                float t = fmaf(p, fw[i], fmaf(q, fb[i], r));
                float v = fmaf(t, fg[i], fe[i]);
                hv[i] = (__bf16)gelu_exact(v);
            }
            *(bf16x8*)(&Als[am][akb]) = hv;
        }

        // ---- stage B (transpose-read of mod_w, cvt to bf16) ----
        {
            const float* src = mod_w + (size_t)(n0b + bn) * K_DIM + k0 + bkh;
            float4 v0 = *(const float4*)(src);
            float4 v1 = *(const float4*)(src + 4);
            float4 v2 = *(const float4*)(src + 8);
            float4 v3 = *(const float4*)(src + 12);
            bf16x8 h0, h1;
            h0[0] = (__bf16)v0.x; h0[1] = (__bf16)v0.y; h0[2] = (__bf16)v0.z; h0[3] = (__bf16)v0.w;
            h0[4] = (__bf16)v1.x; h0[5] = (__bf16)v1.y; h0[6] = (__bf16)v1.z; h0[7] = (__bf16)v1.w;
            h1[0] = (__bf16)v2.x; h1[1] = (__bf16)v2.y; h1[2] = (__bf16)v2.z; h1[3] = (__bf16)v2.w;
            h1[4] = (__bf16)v3.x; h1[5] = (__bf16)v3.y; h1[6] = (__bf16)v3.z; h1[7] = (__bf16)v3.w;
            *(bf16x8*)(&Bls[bn][bkh])     = h0;
            *(bf16x8*)(&Bls[bn][bkh + 8]) = h1;
        }
        __syncthreads();

        // ---- MFMA: wave tile 64x64, 16 frags ----
        bf16x8 bfrag[4];
        #pragma unroll
        for (int nt = 0; nt < 4; ++nt)
            bfrag[nt] = *(const bf16x8*)(&Bls[wn * 64 + nt * 16 + lr][lq * 8]);
        #pragma unroll
        for (int mt = 0; mt < 4; ++mt) {
            bf16x8 afrag = *(const bf16x8*)(&Als[wm * 64 + mt * 16 + lr][lq * 8]);
            #pragma unroll
            for (int nt = 0; nt < 4; ++nt)
                acc[mt][nt] = __builtin_amdgcn_mfma_f32_16x16x32_bf16(
                    afrag, bfrag[nt], acc[mt][nt], 0, 0, 0);
        }
        __syncthreads();
    }

    // ---- epilogue: + mod_b, store pre-LN y (fp32) ----
    #pragma unroll
    for (int mt = 0; mt < 4; ++mt) {
        #pragma unroll
        for (int nt = 0; nt < 4; ++nt) {
            const int col = n0b + wn * 64 + nt * 16 + lr;
            const float mbv = mod_b[col];
            const int row = row0 + wm * 64 + mt * 16 + lq * 4;
            #pragma unroll
            for (int r = 0; r < 4; ++r)
                out[(size_t)(row + r) * H_DIM + col] = acc[mt][nt][r] + mbv;
        }
    }
}

// In-place LayerNorm(512) + exact GELU. One wave per row.
__global__ __launch_bounds__(256) void ln_gelu_kernel(
    float* __restrict__ y,
    const float* __restrict__ gamma,
    const float* __restrict__ beta)
{
    const int wave = threadIdx.x >> 6;
    const int lane = threadIdx.x & 63;
    const int row = blockIdx.x * 4 + wave;
    float* p = y + (size_t)row * H_DIM;

    float4 v0 = *(const float4*)(p + lane * 8);
    float4 v1 = *(const float4*)(p + lane * 8 + 4);
    float s  = v0.x + v0.y + v0.z + v0.w + v1.x + v1.y + v1.z + v1.w;
    float ss = 0.f;
    ss = fmaf(v0.x, v0.x, ss); ss = fmaf(v0.y, v0.y, ss);
    ss = fmaf(v0.z, v0.z, ss); ss = fmaf(v0.w, v0.w, ss);
    ss = fmaf(v1.x, v1.x, ss); ss = fmaf(v1.y, v1.y, ss);
    ss = fmaf(v1.z, v1.z, ss); ss = fmaf(v1.w, v1.w, ss);
    #pragma unroll
    for (int off = 32; off; off >>= 1) {
        s  += __shfl_xor(s,  off);
        ss += __shfl_xor(ss, off);
    }
    const float inv_n = 1.0f / (float)H_DIM;
    float mu  = s * inv_n;
    float var = ss * inv_n - mu * mu;
    float inv = rsqrtf(var + EPS);

    float4 g0 = *(const float4*)(gamma + lane * 8);
    float4 g1 = *(const float4*)(gamma + lane * 8 + 4);
    float4 e0 = *(const float4*)(beta + lane * 8);
    float4 e1 = *(const float4*)(beta + lane * 8 + 4);

    float fv[8] = {v0.x, v0.y, v0.z, v0.w, v1.x, v1.y, v1.z, v1.w};
    float fg[8] = {g0.x, g0.y, g0.z, g0.w, g1.x, g1.y, g1.z, g1.w};
    float fe[8] = {e0.x, e0.y, e0.z, e0.w, e1.x, e1.y, e1.z, e1.w};
    float fo[8];
    #pragma unroll
    for (int i = 0; i < 8; ++i) {
        float t = fmaf((fv[i] - mu) * inv, fg[i], fe[i]);
        fo[i] = gelu_exact(t);
    }
    float4 o0 = {fo[0], fo[1], fo[2], fo[3]};
    float4 o1 = {fo[4], fo[5], fo[6], fo[7]};
    *(float4*)(p + lane * 8)     = o0;
    *(float4*)(p + lane * 8 + 4) = o1;
}

extern "C" void kernel_launch(void* const* d_in, const int* in_sizes, int n_in,
                              void* d_out, int out_size, void* d_ws, size_t ws_size,
                              hipStream_t stream) {
    const float* x         = (const float*)d_in[0];
    const float* enc_w     = (const float*)d_in[1];
    const float* enc_b     = (const float*)d_in[2];
    const float* enc_gamma = (const float*)d_in[3];
    const float* enc_beta  = (const float*)d_in[4];
    const float* mod_w     = (const float*)d_in[5];
    const float* mod_b     = (const float*)d_in[6];
    const float* mod_gamma = (const float*)d_in[7];
    const float* mod_beta  = (const float*)d_in[8];
    float* out = (float*)d_out;

    dim3 grid(BS / TM, H_DIM / TN);   // 256 x 2
    fused_gemm_kernel<<<grid, 512, 0, stream>>>(
        x, enc_w, enc_b, enc_gamma, enc_beta, mod_w, mod_b, out);
    ln_gelu_kernel<<<BS / 4, 256, 0, stream>>>(out, mod_gamma, mod_beta);
}

// Round 2
// 343.294 us; speedup vs baseline: 1.3046x; 1.3046x over previous
//
#include <hip/hip_runtime.h>
#include <hip/hip_bf16.h>
#include <math.h>

#define C_CH 8
#define H_DIM 512
#define BS 32768            // B*S
#define K_DIM 4096          // C*H
#define EPS 1e-5f

#define TM 128
#define TN 512
#define TK 32

typedef __bf16 bf16x8 __attribute__((ext_vector_type(8)));
typedef float  floatx4 __attribute__((ext_vector_type(4)));

// tanh-form GELU via hw exp + rcp: gelu(v) ~= v * sigmoid(1.5957691*(v + 0.044715 v^3))
// max abs deviation from exact erf-gelu ~3e-4.
__device__ __forceinline__ float gelu_fast(float v) {
    float x = v * fmaf(v * v, 0.07135481627f, 1.595769122f);
    float e = __expf(-x);                       // v_exp_f32 based
    return v * __builtin_amdgcn_rcpf(1.0f + e); // v_rcp_f32
}

// mod_w fp32 [512][4096] -> bf16 in workspace
__global__ __launch_bounds__(256) void conv_w_kernel(const float* __restrict__ w,
                                                     __bf16* __restrict__ o) {
    int idx = (blockIdx.x * 256 + threadIdx.x) * 8;
    float4 a = *(const float4*)(w + idx);
    float4 b = *(const float4*)(w + idx + 4);
    bf16x8 h;
    h[0] = (__bf16)a.x; h[1] = (__bf16)a.y; h[2] = (__bf16)a.z; h[3] = (__bf16)a.w;
    h[4] = (__bf16)b.x; h[5] = (__bf16)b.y; h[6] = (__bf16)b.z; h[7] = (__bf16)b.w;
    *(bf16x8*)(o + idx) = h;
}

// Fused: analytic enc-LN -> gelu -> GEMM(mod_w^T) -> +mod_b -> LayerNorm -> gelu -> out
// One block owns 128 full output rows (TN == H_DIM == 512).
__global__ __launch_bounds__(512, 2) void fused_gemm_kernel(
    const float* __restrict__ x,
    const float* __restrict__ enc_w,
    const float* __restrict__ enc_b,
    const float* __restrict__ enc_gamma,
    const float* __restrict__ enc_beta,
    const float* __restrict__ mod_w,      // fp32 fallback
    const __bf16* __restrict__ Wb,        // bf16 pre-converted (may be unused)
    const float* __restrict__ mod_b,
    const float* __restrict__ mod_gamma,
    const float* __restrict__ mod_beta,
    float* __restrict__ out,
    int use_ws)
{
    __shared__ float stats[C_CH][5];
    __shared__ float pS[C_CH][TM];
    __shared__ float qS[C_CH][TM];
    __shared__ float rS[C_CH][TM];
    // chunked fragment-contiguous layouts: chunk(row, kquad) at (row*4+quad)*8 elems
    __shared__ __align__(16) __bf16 Als[TM * TK];   // 8 KB
    __shared__ __align__(16) __bf16 Bls[TN * TK];   // 32 KB
    __shared__ float redS[TM][4];
    __shared__ float redQ[TM][4];
    __shared__ float muS[TM];
    __shared__ float invS[TM];

    const int tid  = threadIdx.x;
    const int wave = tid >> 6;
    const int lane = tid & 63;

    // ---- per-channel encoder stats (8 waves <-> 8 channels) ----
    {
        const int c = wave;
        float sw = 0.f, sb = 0.f, sww = 0.f, sbb = 0.f, swb = 0.f;
        for (int j = lane; j < H_DIM; j += 64) {
            float w = enc_w[c * H_DIM + j];
            float b = enc_b[c * H_DIM + j];
            sw += w; sb += b;
            sww = fmaf(w, w, sww);
            sbb = fmaf(b, b, sbb);
            swb = fmaf(w, b, swb);
        }
        #pragma unroll
        for (int off = 32; off; off >>= 1) {
            sw  += __shfl_xor(sw,  off);
            sb  += __shfl_xor(sb,  off);
            sww += __shfl_xor(sww, off);
            sbb += __shfl_xor(sbb, off);
            swb += __shfl_xor(swb, off);
        }
        if (lane == 0) {
            const float inv = 1.0f / (float)H_DIM;
            float mw = sw * inv, mb = sb * inv;
            stats[c][0] = mw;
            stats[c][1] = mb;
            stats[c][2] = sww * inv - mw * mw;
            stats[c][3] = sbb * inv - mb * mb;
            stats[c][4] = swb * inv - mw * mb;
        }
    }
    __syncthreads();

    // ---- per-(channel,row) p,q,r ----
    const int row0 = blockIdx.x * TM;
    for (int idx = tid; idx < C_CH * TM; idx += 512) {
        int c = idx >> 7;
        int m = idx & (TM - 1);
        float xv = x[c * BS + row0 + m];
        float mw = stats[c][0], mb = stats[c][1];
        float vw = stats[c][2], vb = stats[c][3], cwb = stats[c][4];
        float var = fmaf(xv, fmaf(xv, vw, 2.0f * cwb), vb);
        float q = rsqrtf(var + EPS);
        float p = xv * q;
        pS[c][m] = p;
        qS[c][m] = q;
        rS[c][m] = -fmaf(p, mw, q * mb);
    }
    __syncthreads();

    const int wm = wave >> 2;        // 0..1
    const int wn = wave & 3;         // 0..3
    const int lr = lane & 15;
    const int lq = lane >> 4;

    floatx4 acc[4][8];
    #pragma unroll
    for (int i = 0; i < 4; ++i)
        #pragma unroll
        for (int j = 0; j < 8; ++j)
            acc[i][j] = (floatx4){0.f, 0.f, 0.f, 0.f};

    const int arow = tid >> 2;       // 0..127
    const int aq   = tid & 3;        // k-quad 0..3

    for (int kt = 0; kt < K_DIM / TK; ++kt) {
        const int k0 = kt * TK;
        const int c  = k0 >> 9;
        const int jb = k0 & (H_DIM - 1);

        // ---- stage A: compute 8 gelu'd elements, write one 16B chunk ----
        {
            const int j0 = c * H_DIM + jb + aq * 8;
            float4 w0 = *(const float4*)(enc_w + j0);
            float4 w1 = *(const float4*)(enc_w + j0 + 4);
            float4 b0 = *(const float4*)(enc_b + j0);
            float4 b1 = *(const float4*)(enc_b + j0 + 4);
            float4 g0 = *(const float4*)(enc_gamma + j0);
            float4 g1 = *(const float4*)(enc_gamma + j0 + 4);
            float4 e0 = *(const float4*)(enc_beta + j0);
            float4 e1 = *(const float4*)(enc_beta + j0 + 4);
            float p = pS[c][arow], q = qS[c][arow], r = rS[c][arow];
            float fw[8] = {w0.x, w0.y, w0.z, w0.w, w1.x, w1.y, w1.z, w1.w};
            float fb[8] = {b0.x, b0.y, b0.z, b0.w, b1.x, b1.y, b1.z, b1.w};
            float fg[8] = {g0.x, g0.y, g0.z, g0.w, g1.x, g1.y, g1.z, g1.w};
            float fe[8] = {e0.x, e0.y, e0.z, e0.w, e1.x, e1.y, e1.z, e1.w};
            bf16x8 hv;
            #pragma unroll
            for (int i = 0; i < 8; ++i) {
                float t = fmaf(p, fw[i], fmaf(q, fb[i], r));
                float v = fmaf(t, fg[i], fe[i]);
                hv[i] = (__bf16)gelu_fast(v);
            }
            *(bf16x8*)(Als + tid * 8) = hv;   // chunk == tid -> lane-contiguous write
        }

        // ---- stage B: 4 passes, lane-contiguous LDS writes ----
        if (use_ws) {
            #pragma unroll
            for (int i = 0; i < 4; ++i) {
                int col = i * 128 + (tid >> 2);
                bf16x8 v = *(const bf16x8*)(Wb + (size_t)col * K_DIM + k0 + aq * 8);
                *(bf16x8*)(Bls + (i * 512 + tid) * 8) = v;
            }
        } else {
            #pragma unroll
            for (int i = 0; i < 4; ++i) {
                int col = i * 128 + (tid >> 2);
                const float* src = mod_w + (size_t)col * K_DIM + k0 + aq * 8;
                float4 v0 = *(const float4*)(src);
                float4 v1 = *(const float4*)(src + 4);
                bf16x8 h;
                h[0] = (__bf16)v0.x; h[1] = (__bf16)v0.y; h[2] = (__bf16)v0.z; h[3] = (__bf16)v0.w;
                h[4] = (__bf16)v1.x; h[5] = (__bf16)v1.y; h[6] = (__bf16)v1.z; h[7] = (__bf16)v1.w;
                *(bf16x8*)(Bls + (i * 512 + tid) * 8) = h;
            }
        }
        __syncthreads();

        // ---- MFMA: wave tile 64x128 ----
        bf16x8 af[4];
        #pragma unroll
        for (int mt = 0; mt < 4; ++mt)
            af[mt] = *(const bf16x8*)(Als + ((wm * 64 + mt * 16 + lr) * 4 + lq) * 8);
        #pragma unroll
        for (int nt = 0; nt < 8; ++nt) {
            bf16x8 bf = *(const bf16x8*)(Bls + ((wn * 128 + nt * 16 + lr) * 4 + lq) * 8);
            #pragma unroll
            for (int mt = 0; mt < 4; ++mt)
                acc[mt][nt] = __builtin_amdgcn_mfma_f32_16x16x32_bf16(
                    af[mt], bf, acc[mt][nt], 0, 0, 0);
        }
        __syncthreads();
    }

    // ---- fused epilogue: +mod_b, LayerNorm over 512 cols, gelu, store ----
    float mbv[8], gv[8], bev[8];
    #pragma unroll
    for (int nt = 0; nt < 8; ++nt) {
        int col = wn * 128 + nt * 16 + lr;
        mbv[nt] = mod_b[col];
        gv[nt]  = mod_gamma[col];
        bev[nt] = mod_beta[col];
    }
    #pragma unroll
    for (int mt = 0; mt < 4; ++mt)
        #pragma unroll
        for (int nt = 0; nt < 8; ++nt)
            #pragma unroll
            for (int r = 0; r < 4; ++r)
                acc[mt][nt][r] += mbv[nt];

    // per-row partial sums within this wave's 128 cols
    #pragma unroll
    for (int mt = 0; mt < 4; ++mt) {
        #pragma unroll
        for (int r = 0; r < 4; ++r) {
            float s = 0.f, ss = 0.f;
            #pragma unroll
            for (int nt = 0; nt < 8; ++nt) {
                float y = acc[mt][nt][r];
                s += y;
                ss = fmaf(y, y, ss);
            }
            #pragma unroll
            for (int off = 1; off < 16; off <<= 1) {
                s  += __shfl_xor(s,  off);
                ss += __shfl_xor(ss, off);
            }
            if (lr == 0) {
                int row = wm * 64 + mt * 16 + lq * 4 + r;
                redS[row][wn] = s;
                redQ[row][wn] = ss;
            }
        }
    }
    __syncthreads();
    if (tid < TM) {
        float s  = redS[tid][0] + redS[tid][1] + redS[tid][2] + redS[tid][3];
        float ss = redQ[tid][0] + redQ[tid][1] + redQ[tid][2] + redQ[tid][3];
        const float inv_n = 1.0f / (float)H_DIM;
        float mu  = s * inv_n;
        float var = ss * inv_n - mu * mu;
        muS[tid]  = mu;
        invS[tid] = rsqrtf(var + EPS);
    }
    __syncthreads();

    #pragma unroll
    for (int mt = 0; mt < 4; ++mt) {
        #pragma unroll
        for (int r = 0; r < 4; ++r) {
            int row = wm * 64 + mt * 16 + lq * 4 + r;
            float mu  = muS[row];
            float inv = invS[row];
            float* op = out + (size_t)(row0 + row) * H_DIM;
            #pragma unroll
            for (int nt = 0; nt < 8; ++nt) {
                int col = wn * 128 + nt * 16 + lr;
                float t = fmaf((acc[mt][nt][r] - mu) * inv, gv[nt], bev[nt]);
                op[col] = gelu_fast(t);
            }
        }
    }
}

extern "C" void kernel_launch(void* const* d_in, const int* in_sizes, int n_in,
                              void* d_out, int out_size, void* d_ws, size_t ws_size,
                              hipStream_t stream) {
    const float* x         = (const float*)d_in[0];
    const float* enc_w     = (const float*)d_in[1];
    const float* enc_b     = (const float*)d_in[2];
    const float* enc_gamma = (const float*)d_in[3];
    const float* enc_beta  = (const float*)d_in[4];
    const float* mod_w     = (const float*)d_in[5];
    const float* mod_b     = (const float*)d_in[6];
    const float* mod_gamma = (const float*)d_in[7];
    const float* mod_beta  = (const float*)d_in[8];
    float* out = (float*)d_out;

    const size_t wb_bytes = (size_t)H_DIM * K_DIM * sizeof(__bf16);  // 4 MB
    int use_ws = (ws_size >= wb_bytes) ? 1 : 0;
    __bf16* Wb = (__bf16*)d_ws;

    if (use_ws) {
        conv_w_kernel<<<(H_DIM * K_DIM) / (256 * 8), 256, 0, stream>>>(mod_w, Wb);
    }
    fused_gemm_kernel<<<BS / TM, 512, 0, stream>>>(
        x, enc_w, enc_b, enc_gamma, enc_beta, mod_w, Wb,
        mod_b, mod_gamma, mod_beta, out, use_ws);
}

// Round 3
// 313.996 us; speedup vs baseline: 1.4264x; 1.0933x over previous
//
#include <hip/hip_runtime.h>
#include <hip/hip_bf16.h>
#include <math.h>

#define C_CH 8
#define H_DIM 512
#define BS 32768            // B*S
#define K_DIM 4096          // C*H
#define EPS 1e-5f

#define TM 128
#define TK 32
#define NKT (K_DIM / TK)    // 128 K-tiles

typedef __bf16 bf16x8 __attribute__((ext_vector_type(8)));
typedef float  floatx4 __attribute__((ext_vector_type(4)));

// tanh-form GELU via hw exp + rcp; max abs dev from exact erf-gelu ~3e-4.
__device__ __forceinline__ float gelu_fast(float v) {
    float x = v * fmaf(v * v, 0.07135481627f, 1.595769122f);
    float e = __expf(-x);
    return v * __builtin_amdgcn_rcpf(1.0f + e);
}

// mod_w fp32 [512][4096] -> bf16 workspace in MFMA B-fragment chunk layout:
// chunk(kt 0..127, ntile 0..31) of 64 lanes x 16B; lane l holds
// B[col = ntile*16 + (l&15)][k = kt*32 + (l>>4)*8 + i], i=0..7.
__global__ __launch_bounds__(256) void conv_w_kernel(const float* __restrict__ w,
                                                     __bf16* __restrict__ o) {
    int gtid  = blockIdx.x * 256 + threadIdx.x;   // 0..262143
    int lane  = gtid & 63;
    int chunk = gtid >> 6;                        // 0..4095
    int kt    = chunk >> 5;
    int ntile = chunk & 31;
    int col   = ntile * 16 + (lane & 15);
    int k     = kt * 32 + (lane >> 4) * 8;
    const float* src = w + (size_t)col * K_DIM + k;
    float4 a = *(const float4*)src;
    float4 b = *(const float4*)(src + 4);
    bf16x8 h;
    h[0] = (__bf16)a.x; h[1] = (__bf16)a.y; h[2] = (__bf16)a.z; h[3] = (__bf16)a.w;
    h[4] = (__bf16)b.x; h[5] = (__bf16)b.y; h[6] = (__bf16)b.z; h[7] = (__bf16)b.w;
    *(bf16x8*)(o + (size_t)gtid * 8) = h;
}

// Fused: analytic enc-LN -> gelu -> GEMM(mod_w^T) -> +mod_b -> LayerNorm -> gelu.
// One block owns 128 full output rows. B frags load global->VGPR directly
// (no LDS, no barrier); A tile double-buffered in LDS, 1 barrier/iter.
__global__ __launch_bounds__(512, 2) void fused_gemm_kernel(
    const float* __restrict__ x,
    const float* __restrict__ enc_w,
    const float* __restrict__ enc_b,
    const float* __restrict__ enc_gamma,
    const float* __restrict__ enc_beta,
    const float* __restrict__ mod_w,      // fp32 fallback
    const __bf16* __restrict__ Wb,        // bf16 frag-layout (workspace)
    const float* __restrict__ mod_b,
    const float* __restrict__ mod_gamma,
    const float* __restrict__ mod_beta,
    float* __restrict__ out,
    int use_ws)
{
    __shared__ float stats[C_CH][5];
    __shared__ float pS[C_CH][TM];
    __shared__ float qS[C_CH][TM];
    __shared__ float rS[C_CH][TM];
    __shared__ __align__(16) __bf16 Als[2][TM * TK];   // 2 x 8 KB, chunked [row*4+kq]
    __shared__ float redS[TM][4];
    __shared__ float redQ[TM][4];
    __shared__ float muS[TM];
    __shared__ float invS[TM];

    const int tid  = threadIdx.x;
    const int wave = tid >> 6;
    const int lane = tid & 63;

    // ---- per-channel encoder stats (closed-form LN of affine map) ----
    {
        const int c = wave;
        float sw = 0.f, sb = 0.f, sww = 0.f, sbb = 0.f, swb = 0.f;
        for (int j = lane; j < H_DIM; j += 64) {
            float w = enc_w[c * H_DIM + j];
            float b = enc_b[c * H_DIM + j];
            sw += w; sb += b;
            sww = fmaf(w, w, sww);
            sbb = fmaf(b, b, sbb);
            swb = fmaf(w, b, swb);
        }
        #pragma unroll
        for (int off = 32; off; off >>= 1) {
            sw  += __shfl_xor(sw,  off);
            sb  += __shfl_xor(sb,  off);
            sww += __shfl_xor(sww, off);
            sbb += __shfl_xor(sbb, off);
            swb += __shfl_xor(swb, off);
        }
        if (lane == 0) {
            const float inv = 1.0f / (float)H_DIM;
            float mw = sw * inv, mb = sb * inv;
            stats[c][0] = mw;
            stats[c][1] = mb;
            stats[c][2] = sww * inv - mw * mw;
            stats[c][3] = sbb * inv - mb * mb;
            stats[c][4] = swb * inv - mw * mb;
        }
    }
    __syncthreads();

    // ---- per-(channel,row) p,q,r ----
    const int row0 = blockIdx.x * TM;
    for (int idx = tid; idx < C_CH * TM; idx += 512) {
        int c = idx >> 7;
        int m = idx & (TM - 1);
        float xv = x[c * BS + row0 + m];
        float mw = stats[c][0], mb = stats[c][1];
        float vw = stats[c][2], vb = stats[c][3], cwb = stats[c][4];
        float var = fmaf(xv, fmaf(xv, vw, 2.0f * cwb), vb);
        float q = rsqrtf(var + EPS);
        float p = xv * q;
        pS[c][m] = p;
        qS[c][m] = q;
        rS[c][m] = -fmaf(p, mw, q * mb);
    }
    __syncthreads();

    const int wm = wave >> 2;        // 0..1
    const int wn = wave & 3;         // 0..3
    const int lr = lane & 15;
    const int lq = lane >> 4;

    const int arow = tid >> 2;       // 0..127
    const int aq   = tid & 3;        // k-quad 0..3

    floatx4 acc[4][8];
    #pragma unroll
    for (int i = 0; i < 4; ++i)
        #pragma unroll
        for (int j = 0; j < 8; ++j)
            acc[i][j] = (floatx4){0.f, 0.f, 0.f, 0.f};

    // ---- A-stage: gelu(enc-LN) for tile ktn into dst (one 16B chunk/thread) ----
    auto stageA = [&](int ktn, __bf16* dst) {
        const int k0 = ktn * TK;
        const int c  = k0 >> 9;
        const int j0 = c * H_DIM + (k0 & (H_DIM - 1)) + aq * 8;
        float4 w0 = *(const float4*)(enc_w + j0);
        float4 w1 = *(const float4*)(enc_w + j0 + 4);
        float4 b0 = *(const float4*)(enc_b + j0);
        float4 b1 = *(const float4*)(enc_b + j0 + 4);
        float4 g0 = *(const float4*)(enc_gamma + j0);
        float4 g1 = *(const float4*)(enc_gamma + j0 + 4);
        float4 e0 = *(const float4*)(enc_beta + j0);
        float4 e1 = *(const float4*)(enc_beta + j0 + 4);
        float p = pS[c][arow], q = qS[c][arow], r = rS[c][arow];
        float fw[8] = {w0.x, w0.y, w0.z, w0.w, w1.x, w1.y, w1.z, w1.w};
        float fb[8] = {b0.x, b0.y, b0.z, b0.w, b1.x, b1.y, b1.z, b1.w};
        float fg[8] = {g0.x, g0.y, g0.z, g0.w, g1.x, g1.y, g1.z, g1.w};
        float fe[8] = {e0.x, e0.y, e0.z, e0.w, e1.x, e1.y, e1.z, e1.w};
        bf16x8 hv;
        #pragma unroll
        for (int i = 0; i < 8; ++i) {
            float t = fmaf(p, fw[i], fmaf(q, fb[i], r));
            float v = fmaf(t, fg[i], fe[i]);
            hv[i] = (__bf16)gelu_fast(v);
        }
        *(bf16x8*)(dst + tid * 8) = hv;
    };

    stageA(0, Als[0]);
    __syncthreads();

    for (int kt = 0; kt < NKT; ++kt) {
        // ---- B frags: direct global->VGPR from frag-layout Wb (no barrier) ----
        bf16x8 bfr[8];
        if (use_ws) {
            const size_t cbase = (size_t)(kt * 32 + wn * 8) * 64 + lane;
            #pragma unroll
            for (int nt = 0; nt < 8; ++nt)
                bfr[nt] = *(const bf16x8*)(Wb + (cbase + (size_t)nt * 64) * 8);
        } else {
            const int kk = kt * 32 + lq * 8;
            #pragma unroll
            for (int nt = 0; nt < 8; ++nt) {
                int col = wn * 128 + nt * 16 + lr;
                const float* src = mod_w + (size_t)col * K_DIM + kk;
                float4 a = *(const float4*)src;
                float4 b = *(const float4*)(src + 4);
                bf16x8 h;
                h[0] = (__bf16)a.x; h[1] = (__bf16)a.y; h[2] = (__bf16)a.z; h[3] = (__bf16)a.w;
                h[4] = (__bf16)b.x; h[5] = (__bf16)b.y; h[6] = (__bf16)b.z; h[7] = (__bf16)b.w;
                bfr[nt] = h;
            }
        }

        // ---- stage A for next tile into the other buffer (hides B latency) ----
        if (kt + 1 < NKT) stageA(kt + 1, Als[(kt + 1) & 1]);

        // ---- A frag reads + MFMA (wave tile 64x128) ----
        const __bf16* Acur = Als[kt & 1];
        bf16x8 af[4];
        #pragma unroll
        for (int mt = 0; mt < 4; ++mt)
            af[mt] = *(const bf16x8*)(Acur + ((wm * 64 + mt * 16 + lr) * 4 + lq) * 8);
        #pragma unroll
        for (int nt = 0; nt < 8; ++nt)
            #pragma unroll
            for (int mt = 0; mt < 4; ++mt)
                acc[mt][nt] = __builtin_amdgcn_mfma_f32_16x16x32_bf16(
                    af[mt], bfr[nt], acc[mt][nt], 0, 0, 0);

        __syncthreads();
    }

    // ---- fused epilogue: +mod_b, LayerNorm over 512 cols, gelu, store ----
    float mbv[8], gv[8], bev[8];
    #pragma unroll
    for (int nt = 0; nt < 8; ++nt) {
        int col = wn * 128 + nt * 16 + lr;
        mbv[nt] = mod_b[col];
        gv[nt]  = mod_gamma[col];
        bev[nt] = mod_beta[col];
    }
    #pragma unroll
    for (int mt = 0; mt < 4; ++mt)
        #pragma unroll
        for (int nt = 0; nt < 8; ++nt)
            #pragma unroll
            for (int r = 0; r < 4; ++r)
                acc[mt][nt][r] += mbv[nt];

    #pragma unroll
    for (int mt = 0; mt < 4; ++mt) {
        #pragma unroll
        for (int r = 0; r < 4; ++r) {
            float s = 0.f, ss = 0.f;
            #pragma unroll
            for (int nt = 0; nt < 8; ++nt) {
                float y = acc[mt][nt][r];
                s += y;
                ss = fmaf(y, y, ss);
            }
            #pragma unroll
            for (int off = 1; off < 16; off <<= 1) {
                s  += __shfl_xor(s,  off);
                ss += __shfl_xor(ss, off);
            }
            if (lr == 0) {
                int row = wm * 64 + mt * 16 + lq * 4 + r;
                redS[row][wn] = s;
                redQ[row][wn] = ss;
            }
        }
    }
    __syncthreads();
    if (tid < TM) {
        float s  = redS[tid][0] + redS[tid][1] + redS[tid][2] + redS[tid][3];
        float ss = redQ[tid][0] + redQ[tid][1] + redQ[tid][2] + redQ[tid][3];
        const float inv_n = 1.0f / (float)H_DIM;
        float mu  = s * inv_n;
        float var = ss * inv_n - mu * mu;
        muS[tid]  = mu;
        invS[tid] = rsqrtf(var + EPS);
    }
    __syncthreads();

    #pragma unroll
    for (int mt = 0; mt < 4; ++mt) {
        #pragma unroll
        for (int r = 0; r < 4; ++r) {
            int row = wm * 64 + mt * 16 + lq * 4 + r;
            float mu  = muS[row];
            float inv = invS[row];
            float* op = out + (size_t)(row0 + row) * H_DIM;
            #pragma unroll
            for (int nt = 0; nt < 8; ++nt) {
                int col = wn * 128 + nt * 16 + lr;
                float t = fmaf((acc[mt][nt][r] - mu) * inv, gv[nt], bev[nt]);
                op[col] = gelu_fast(t);
            }
        }
    }
}

extern "C" void kernel_launch(void* const* d_in, const int* in_sizes, int n_in,
                              void* d_out, int out_size, void* d_ws, size_t ws_size,
                              hipStream_t stream) {
    const float* x         = (const float*)d_in[0];
    const float* enc_w     = (const float*)d_in[1];
    const float* enc_b     = (const float*)d_in[2];
    const float* enc_gamma = (const float*)d_in[3];
    const float* enc_beta  = (const float*)d_in[4];
    const float* mod_w     = (const float*)d_in[5];
    const float* mod_b     = (const float*)d_in[6];
    const float* mod_gamma = (const float*)d_in[7];
    const float* mod_beta  = (const float*)d_in[8];
    float* out = (float*)d_out;

    const size_t wb_bytes = (size_t)H_DIM * K_DIM * sizeof(__bf16);  // 4 MB
    int use_ws = (ws_size >= wb_bytes) ? 1 : 0;
    __bf16* Wb = (__bf16*)d_ws;

    if (use_ws) {
        conv_w_kernel<<<(H_DIM * K_DIM) / (256 * 8), 256, 0, stream>>>(mod_w, Wb);
    }
    fused_gemm_kernel<<<BS / TM, 512, 0, stream>>>(
        x, enc_w, enc_b, enc_gamma, enc_beta, mod_w, Wb,
        mod_b, mod_gamma, mod_beta, out, use_ws);
}

// Round 4
// 285.622 us; speedup vs baseline: 1.5681x; 1.0993x over previous
//
#include <hip/hip_runtime.h>
#include <hip/hip_bf16.h>
#include <math.h>

#define C_CH 8
#define H_DIM 512
#define BS 32768            // B*S
#define K_DIM 4096          // C*H
#define EPS 1e-5f

#define TM 128
#define TK 32
#define NKT (K_DIM / TK)    // 128 K-tiles

typedef __bf16 bf16x8 __attribute__((ext_vector_type(8)));
typedef float  floatx4 __attribute__((ext_vector_type(4)));

// tanh-form GELU via hw exp + rcp; max abs dev from exact erf-gelu ~3e-4.
__device__ __forceinline__ float gelu_fast(float v) {
    float x = v * fmaf(v * v, 0.07135481627f, 1.595769122f);
    float e = __expf(-x);
    return v * __builtin_amdgcn_rcpf(1.0f + e);
}

// mod_w fp32 [512][4096] -> bf16 workspace in MFMA B-fragment chunk layout:
// chunk(kt 0..127, ntile 0..31) of 64 lanes x 16B; lane l holds
// B[col = ntile*16 + (l&15)][k = kt*32 + (l>>4)*8 + i], i=0..7.
__global__ __launch_bounds__(256) void conv_w_kernel(const float* __restrict__ w,
                                                     __bf16* __restrict__ o) {
    int gtid  = blockIdx.x * 256 + threadIdx.x;   // 0..262143
    int lane  = gtid & 63;
    int chunk = gtid >> 6;                        // 0..4095
    int kt    = chunk >> 5;
    int ntile = chunk & 31;
    int col   = ntile * 16 + (lane & 15);
    int k     = kt * 32 + (lane >> 4) * 8;
    const float* src = w + (size_t)col * K_DIM + k;
    float4 a = *(const float4*)src;
    float4 b = *(const float4*)(src + 4);
    bf16x8 h;
    h[0] = (__bf16)a.x; h[1] = (__bf16)a.y; h[2] = (__bf16)a.z; h[3] = (__bf16)a.w;
    h[4] = (__bf16)b.x; h[5] = (__bf16)b.y; h[6] = (__bf16)b.z; h[7] = (__bf16)b.w;
    *(bf16x8*)(o + (size_t)gtid * 8) = h;
}

// Fused: analytic enc-LN -> gelu -> GEMM(mod_w^T) -> +mod_b -> LayerNorm -> gelu.
// One block owns 128 full output rows. B frags stream global(L2)->VGPR with a
// two-half-buffer software pipeline so loads stay in flight during MFMA.
// A tile double-buffered in LDS with XOR bank swizzle, 1 barrier/iter.
template <int USE_WS>
__global__ __launch_bounds__(512, 2) void fused_gemm_kernel(
    const float* __restrict__ x,
    const float* __restrict__ enc_w,
    const float* __restrict__ enc_b,
    const float* __restrict__ enc_gamma,
    const float* __restrict__ enc_beta,
    const float* __restrict__ mod_w,      // fp32 fallback
    const __bf16* __restrict__ Wb,        // bf16 frag-layout (workspace)
    const float* __restrict__ mod_b,
    const float* __restrict__ mod_gamma,
    const float* __restrict__ mod_beta,
    float* __restrict__ out)
{
    __shared__ float stats[C_CH][5];
    __shared__ float pS[C_CH][TM];
    __shared__ float qS[C_CH][TM];
    __shared__ float rS[C_CH][TM];
    __shared__ __align__(16) __bf16 Als[2][TM * TK];   // 2 x 8 KB, swizzled chunks
    __shared__ float redS[TM][4];
    __shared__ float redQ[TM][4];
    __shared__ float muS[TM];
    __shared__ float invS[TM];

    const int tid  = threadIdx.x;
    const int wave = tid >> 6;
    const int lane = tid & 63;

    // ---- per-channel encoder stats (closed-form LN of affine map) ----
    {
        const int c = wave;
        float sw = 0.f, sb = 0.f, sww = 0.f, sbb = 0.f, swb = 0.f;
        for (int j = lane; j < H_DIM; j += 64) {
            float w = enc_w[c * H_DIM + j];
            float b = enc_b[c * H_DIM + j];
            sw += w; sb += b;
            sww = fmaf(w, w, sww);
            sbb = fmaf(b, b, sbb);
            swb = fmaf(w, b, swb);
        }
        #pragma unroll
        for (int off = 32; off; off >>= 1) {
            sw  += __shfl_xor(sw,  off);
            sb  += __shfl_xor(sb,  off);
            sww += __shfl_xor(sww, off);
            sbb += __shfl_xor(sbb, off);
            swb += __shfl_xor(swb, off);
        }
        if (lane == 0) {
            const float inv = 1.0f / (float)H_DIM;
            float mw = sw * inv, mb = sb * inv;
            stats[c][0] = mw;
            stats[c][1] = mb;
            stats[c][2] = sww * inv - mw * mw;
            stats[c][3] = sbb * inv - mb * mb;
            stats[c][4] = swb * inv - mw * mb;
        }
    }
    __syncthreads();

    // ---- per-(channel,row) p,q,r ----
    const int row0 = blockIdx.x * TM;
    for (int idx = tid; idx < C_CH * TM; idx += 512) {
        int c = idx >> 7;
        int m = idx & (TM - 1);
        float xv = x[c * BS + row0 + m];
        float mw = stats[c][0], mb = stats[c][1];
        float vw = stats[c][2], vb = stats[c][3], cwb = stats[c][4];
        float var = fmaf(xv, fmaf(xv, vw, 2.0f * cwb), vb);
        float q = rsqrtf(var + EPS);
        float p = xv * q;
        pS[c][m] = p;
        qS[c][m] = q;
        rS[c][m] = -fmaf(p, mw, q * mb);
    }
    __syncthreads();

    const int wm = wave >> 2;        // 0..1
    const int wn = wave & 3;         // 0..3
    const int lr = lane & 15;
    const int lq = lane >> 4;

    const int arow = tid >> 2;       // 0..127
    const int aq   = tid & 3;        // k-quad 0..3
    const int wchunk = arow * 4 + (aq ^ ((arow >> 1) & 3));   // XOR bank swizzle

    floatx4 acc[4][8];
    #pragma unroll
    for (int i = 0; i < 4; ++i)
        #pragma unroll
        for (int j = 0; j < 8; ++j)
            acc[i][j] = (floatx4){0.f, 0.f, 0.f, 0.f};

    // ---- A-stage: gelu(enc-LN) for tile ktn into dst (one 16B chunk/thread) ----
    auto stageA = [&](int ktn, __bf16* dst) {
        const int k0 = ktn * TK;
        const int c  = k0 >> 9;
        const int j0 = c * H_DIM + (k0 & (H_DIM - 1)) + aq * 8;
        float p = pS[c][arow], q = qS[c][arow], r = rS[c][arow];
        bf16x8 hv;
        #pragma unroll
        for (int h = 0; h < 2; ++h) {
            float4 w = *(const float4*)(enc_w + j0 + h * 4);
            float4 b = *(const float4*)(enc_b + j0 + h * 4);
            float4 g = *(const float4*)(enc_gamma + j0 + h * 4);
            float4 e = *(const float4*)(enc_beta + j0 + h * 4);
            float fw[4] = {w.x, w.y, w.z, w.w};
            float fb[4] = {b.x, b.y, b.z, b.w};
            float fg[4] = {g.x, g.y, g.z, g.w};
            float fe[4] = {e.x, e.y, e.z, e.w};
            #pragma unroll
            for (int i = 0; i < 4; ++i) {
                float t = fmaf(p, fw[i], fmaf(q, fb[i], r));
                float v = fmaf(t, fg[i], fe[i]);
                hv[h * 4 + i] = (__bf16)gelu_fast(v);
            }
        }
        *(bf16x8*)(dst + wchunk * 8) = hv;
    };

    // ---- B-frag loader: 4 frags (one n-half of the wave's 128 cols) ----
    auto loadB = [&](int ktn, int half, bf16x8* dst) {
        if (USE_WS) {
            const __bf16* base = Wb + ((size_t)(ktn * 32 + wn * 8 + half * 4) * 64 + lane) * 8;
            #pragma unroll
            for (int nt = 0; nt < 4; ++nt)
                dst[nt] = *(const bf16x8*)(base + (size_t)nt * 64 * 8);
        } else {
            const int kk = ktn * 32 + lq * 8;
            #pragma unroll
            for (int nt = 0; nt < 4; ++nt) {
                int col = wn * 128 + (half * 4 + nt) * 16 + lr;
                const float* src = mod_w + (size_t)col * K_DIM + kk;
                float4 a = *(const float4*)src;
                float4 b = *(const float4*)(src + 4);
                bf16x8 h;
                h[0] = (__bf16)a.x; h[1] = (__bf16)a.y; h[2] = (__bf16)a.z; h[3] = (__bf16)a.w;
                h[4] = (__bf16)b.x; h[5] = (__bf16)b.y; h[6] = (__bf16)b.z; h[7] = (__bf16)b.w;
                dst[nt] = h;
            }
        }
    };

    bf16x8 bfrP[4], bfrQ[4];
    loadB(0, 0, bfrP);          // prologue: first half of iter-0 B in flight
    stageA(0, Als[0]);
    __syncthreads();

    for (int kt = 0; kt < NKT; ++kt) {
        // issue second-half B for this iter (covered by stageA VALU)
        loadB(kt, 1, bfrQ);

        // stage next A tile into the other LDS buffer
        if (kt + 1 < NKT) stageA(kt + 1, Als[(kt + 1) & 1]);

        // A fragment reads (swizzled, 2-way conflict = free)
        const __bf16* Acur = Als[kt & 1];
        bf16x8 af[4];
        #pragma unroll
        for (int mt = 0; mt < 4; ++mt) {
            int row = wm * 64 + mt * 16 + lr;
            int chunk = row * 4 + (lq ^ ((row >> 1) & 3));
            af[mt] = *(const bf16x8*)(Acur + chunk * 8);
        }

        // MFMA half 1: bfrP (loaded one phase earlier, already resident)
        #pragma unroll
        for (int mt = 0; mt < 4; ++mt)
            #pragma unroll
            for (int nt = 0; nt < 4; ++nt)
                acc[mt][nt] = __builtin_amdgcn_mfma_f32_16x16x32_bf16(
                    af[mt], bfrP[nt], acc[mt][nt], 0, 0, 0);

        // issue first-half B for NEXT iter; stays in flight across the barrier
        if (kt + 1 < NKT) loadB(kt + 1, 0, bfrP);

        // MFMA half 2: bfrQ (arrived during stageA)
        #pragma unroll
        for (int mt = 0; mt < 4; ++mt)
            #pragma unroll
            for (int nt = 0; nt < 4; ++nt)
                acc[mt][nt + 4] = __builtin_amdgcn_mfma_f32_16x16x32_bf16(
                    af[mt], bfrQ[nt], acc[mt][nt + 4], 0, 0, 0);

        __syncthreads();
    }

    // ---- fused epilogue: +mod_b, LayerNorm over 512 cols, gelu, store ----
    float mbv[8], gv[8], bev[8];
    #pragma unroll
    for (int nt = 0; nt < 8; ++nt) {
        int col = wn * 128 + nt * 16 + lr;
        mbv[nt] = mod_b[col];
        gv[nt]  = mod_gamma[col];
        bev[nt] = mod_beta[col];
    }
    #pragma unroll
    for (int mt = 0; mt < 4; ++mt)
        #pragma unroll
        for (int nt = 0; nt < 8; ++nt)
            #pragma unroll
            for (int r = 0; r < 4; ++r)
                acc[mt][nt][r] += mbv[nt];

    #pragma unroll
    for (int mt = 0; mt < 4; ++mt) {
        #pragma unroll
        for (int r = 0; r < 4; ++r) {
            float s = 0.f, ss = 0.f;
            #pragma unroll
            for (int nt = 0; nt < 8; ++nt) {
                float y = acc[mt][nt][r];
                s += y;
                ss = fmaf(y, y, ss);
            }
            #pragma unroll
            for (int off = 1; off < 16; off <<= 1) {
                s  += __shfl_xor(s,  off);
                ss += __shfl_xor(ss, off);
            }
            if (lr == 0) {
                int row = wm * 64 + mt * 16 + lq * 4 + r;
                redS[row][wn] = s;
                redQ[row][wn] = ss;
            }
        }
    }
    __syncthreads();
    if (tid < TM) {
        float s  = redS[tid][0] + redS[tid][1] + redS[tid][2] + redS[tid][3];
        float ss = redQ[tid][0] + redQ[tid][1] + redQ[tid][2] + redQ[tid][3];
        const float inv_n = 1.0f / (float)H_DIM;
        float mu  = s * inv_n;
        float var = ss * inv_n - mu * mu;
        muS[tid]  = mu;
        invS[tid] = rsqrtf(var + EPS);
    }
    __syncthreads();

    #pragma unroll
    for (int mt = 0; mt < 4; ++mt) {
        #pragma unroll
        for (int r = 0; r < 4; ++r) {
            int row = wm * 64 + mt * 16 + lq * 4 + r;
            float mu  = muS[row];
            float inv = invS[row];
            float* op = out + (size_t)(row0 + row) * H_DIM;
            #pragma unroll
            for (int nt = 0; nt < 8; ++nt) {
                int col = wn * 128 + nt * 16 + lr;
                float t = fmaf((acc[mt][nt][r] - mu) * inv, gv[nt], bev[nt]);
                op[col] = gelu_fast(t);
            }
        }
    }
}

extern "C" void kernel_launch(void* const* d_in, const int* in_sizes, int n_in,
                              void* d_out, int out_size, void* d_ws, size_t ws_size,
                              hipStream_t stream) {
    const float* x         = (const float*)d_in[0];
    const float* enc_w     = (const float*)d_in[1];
    const float* enc_b     = (const float*)d_in[2];
    const float* enc_gamma = (const float*)d_in[3];
    const float* enc_beta  = (const float*)d_in[4];
    const float* mod_w     = (const float*)d_in[5];
    const float* mod_b     = (const float*)d_in[6];
    const float* mod_gamma = (const float*)d_in[7];
    const float* mod_beta  = (const float*)d_in[8];
    float* out = (float*)d_out;

    const size_t wb_bytes = (size_t)H_DIM * K_DIM * sizeof(__bf16);  // 4 MB
    int use_ws = (ws_size >= wb_bytes) ? 1 : 0;
    __bf16* Wb = (__bf16*)d_ws;

    if (use_ws) {
        conv_w_kernel<<<(H_DIM * K_DIM) / (256 * 8), 256, 0, stream>>>(mod_w, Wb);
        fused_gemm_kernel<1><<<BS / TM, 512, 0, stream>>>(
            x, enc_w, enc_b, enc_gamma, enc_beta, mod_w, Wb,
            mod_b, mod_gamma, mod_beta, out);
    } else {
        fused_gemm_kernel<0><<<BS / TM, 512, 0, stream>>>(
            x, enc_w, enc_b, enc_gamma, enc_beta, mod_w, Wb,
            mod_b, mod_gamma, mod_beta, out);
    }
}

// Round 5
// 277.963 us; speedup vs baseline: 1.6113x; 1.0276x over previous
//
#include <hip/hip_runtime.h>
#include <hip/hip_bf16.h>
#include <math.h>

#define C_CH 8
#define H_DIM 512
#define BS 32768            // B*S
#define K_DIM 4096          // C*H
#define EPS 1e-5f

#define TM 64
#define TK 32
#define NKT (K_DIM / TK)    // 128 K-tiles

typedef __bf16 bf16x8 __attribute__((ext_vector_type(8)));
typedef float  floatx4 __attribute__((ext_vector_type(4)));

// tanh-form GELU via hw exp + rcp; max abs dev from exact erf-gelu ~3e-4.
__device__ __forceinline__ float gelu_fast(float v) {
    float x = v * fmaf(v * v, 0.07135481627f, 1.595769122f);
    float e = __expf(-x);
    return v * __builtin_amdgcn_rcpf(1.0f + e);
}

// mod_w fp32 [512][4096] -> bf16 workspace in MFMA B-fragment chunk layout:
// chunk(kt 0..127, ntile 0..31) of 64 lanes x 16B; lane l holds
// B[col = ntile*16 + (l&15)][k = kt*32 + (l>>4)*8 + i], i=0..7.
__global__ __launch_bounds__(256) void conv_w_kernel(const float* __restrict__ w,
                                                     __bf16* __restrict__ o) {
    int gtid  = blockIdx.x * 256 + threadIdx.x;   // 0..262143
    int lane  = gtid & 63;
    int chunk = gtid >> 6;                        // 0..4095
    int kt    = chunk >> 5;
    int ntile = chunk & 31;
    int col   = ntile * 16 + (lane & 15);
    int k     = kt * 32 + (lane >> 4) * 8;
    const float* src = w + (size_t)col * K_DIM + k;
    float4 a = *(const float4*)src;
    float4 b = *(const float4*)(src + 4);
    bf16x8 h;
    h[0] = (__bf16)a.x; h[1] = (__bf16)a.y; h[2] = (__bf16)a.z; h[3] = (__bf16)a.w;
    h[4] = (__bf16)b.x; h[5] = (__bf16)b.y; h[6] = (__bf16)b.z; h[7] = (__bf16)b.w;
    *(bf16x8*)(o + (size_t)gtid * 8) = h;
}

// Fused: analytic enc-LN -> gelu -> GEMM(mod_w^T) -> +mod_b -> LayerNorm -> gelu.
// TM=64 rows/block, 4 waves, grid 512 -> 2 independent blocks per CU so one
// block's barrier drain overlaps the other's MFMA/VALU. B frags stream
// global(L2)->VGPR; A tile double-buffered in LDS with XOR swizzle.
template <int USE_WS>
__global__ __launch_bounds__(256, 2) void fused_gemm_kernel(
    const float* __restrict__ x,
    const float* __restrict__ enc_w,
    const float* __restrict__ enc_b,
    const float* __restrict__ enc_gamma,
    const float* __restrict__ enc_beta,
    const float* __restrict__ mod_w,      // fp32 fallback
    const __bf16* __restrict__ Wb,        // bf16 frag-layout (workspace)
    const float* __restrict__ mod_b,
    const float* __restrict__ mod_gamma,
    const float* __restrict__ mod_beta,
    float* __restrict__ out)
{
    __shared__ float stats[C_CH][5];
    __shared__ float pS[C_CH][TM];
    __shared__ float qS[C_CH][TM];
    __shared__ float rS[C_CH][TM];
    __shared__ __align__(16) __bf16 Als[2][TM * TK];   // 2 x 4 KB, swizzled chunks
    __shared__ float redS[TM][4];
    __shared__ float redQ[TM][4];
    __shared__ float muS[TM];
    __shared__ float invS[TM];

    const int tid  = threadIdx.x;
    const int wave = tid >> 6;        // 0..3
    const int lane = tid & 63;

    // ---- per-channel encoder stats (closed-form LN of affine map) ----
    for (int c = wave; c < C_CH; c += 4) {
        float sw = 0.f, sb = 0.f, sww = 0.f, sbb = 0.f, swb = 0.f;
        for (int j = lane; j < H_DIM; j += 64) {
            float w = enc_w[c * H_DIM + j];
            float b = enc_b[c * H_DIM + j];
            sw += w; sb += b;
            sww = fmaf(w, w, sww);
            sbb = fmaf(b, b, sbb);
            swb = fmaf(w, b, swb);
        }
        #pragma unroll
        for (int off = 32; off; off >>= 1) {
            sw  += __shfl_xor(sw,  off);
            sb  += __shfl_xor(sb,  off);
            sww += __shfl_xor(sww, off);
            sbb += __shfl_xor(sbb, off);
            swb += __shfl_xor(swb, off);
        }
        if (lane == 0) {
            const float inv = 1.0f / (float)H_DIM;
            float mw = sw * inv, mb = sb * inv;
            stats[c][0] = mw;
            stats[c][1] = mb;
            stats[c][2] = sww * inv - mw * mw;
            stats[c][3] = sbb * inv - mb * mb;
            stats[c][4] = swb * inv - mw * mb;
        }
    }
    __syncthreads();

    // ---- per-(channel,row) p,q,r ----
    const int row0 = blockIdx.x * TM;
    for (int idx = tid; idx < C_CH * TM; idx += 256) {
        int c = idx >> 6;            // / TM (TM==64)
        int m = idx & (TM - 1);
        float xv = x[c * BS + row0 + m];
        float mw = stats[c][0], mb = stats[c][1];
        float vw = stats[c][2], vb = stats[c][3], cwb = stats[c][4];
        float var = fmaf(xv, fmaf(xv, vw, 2.0f * cwb), vb);
        float q = rsqrtf(var + EPS);
        float p = xv * q;
        pS[c][m] = p;
        qS[c][m] = q;
        rS[c][m] = -fmaf(p, mw, q * mb);
    }
    __syncthreads();

    const int wn = wave;             // wave tile: 64 rows x 128 cols
    const int lr = lane & 15;
    const int lq = lane >> 4;

    const int arow = tid >> 2;       // 0..63
    const int aq   = tid & 3;        // k-quad 0..3
    const int wchunk = arow * 4 + (aq ^ ((arow >> 1) & 3));   // XOR bank swizzle

    floatx4 acc[4][8];
    #pragma unroll
    for (int i = 0; i < 4; ++i)
        #pragma unroll
        for (int j = 0; j < 8; ++j)
            acc[i][j] = (floatx4){0.f, 0.f, 0.f, 0.f};

    // ---- A-stage: gelu(enc-LN) for tile ktn into dst (one 16B chunk/thread) ----
    auto stageA = [&](int ktn, __bf16* dst) {
        const int k0 = ktn * TK;
        const int c  = k0 >> 9;
        const int j0 = c * H_DIM + (k0 & (H_DIM - 1)) + aq * 8;
        float p = pS[c][arow], q = qS[c][arow], r = rS[c][arow];
        bf16x8 hv;
        #pragma unroll
        for (int h = 0; h < 2; ++h) {
            float4 w = *(const float4*)(enc_w + j0 + h * 4);
            float4 b = *(const float4*)(enc_b + j0 + h * 4);
            float4 g = *(const float4*)(enc_gamma + j0 + h * 4);
            float4 e = *(const float4*)(enc_beta + j0 + h * 4);
            float fw[4] = {w.x, w.y, w.z, w.w};
            float fb[4] = {b.x, b.y, b.z, b.w};
            float fg[4] = {g.x, g.y, g.z, g.w};
            float fe[4] = {e.x, e.y, e.z, e.w};
            #pragma unroll
            for (int i = 0; i < 4; ++i) {
                float t = fmaf(p, fw[i], fmaf(q, fb[i], r));
                float v = fmaf(t, fg[i], fe[i]);
                hv[h * 4 + i] = (__bf16)gelu_fast(v);
            }
        }
        *(bf16x8*)(dst + wchunk * 8) = hv;
    };

    // ---- B-frag loader: 4 frags (one n-half of the wave's 128 cols) ----
    auto loadB = [&](int ktn, int half, bf16x8* dst) {
        if (USE_WS) {
            const __bf16* base = Wb + ((size_t)(ktn * 32 + wn * 8 + half * 4) * 64 + lane) * 8;
            #pragma unroll
            for (int nt = 0; nt < 4; ++nt)
                dst[nt] = *(const bf16x8*)(base + (size_t)nt * 64 * 8);
        } else {
            const int kk = ktn * 32 + lq * 8;
            #pragma unroll
            for (int nt = 0; nt < 4; ++nt) {
                int col = wn * 128 + (half * 4 + nt) * 16 + lr;
                const float* src = mod_w + (size_t)col * K_DIM + kk;
                float4 a = *(const float4*)src;
                float4 b = *(const float4*)(src + 4);
                bf16x8 h;
                h[0] = (__bf16)a.x; h[1] = (__bf16)a.y; h[2] = (__bf16)a.z; h[3] = (__bf16)a.w;
                h[4] = (__bf16)b.x; h[5] = (__bf16)b.y; h[6] = (__bf16)b.z; h[7] = (__bf16)b.w;
                dst[nt] = h;
            }
        }
    };

    bf16x8 bfrP[4], bfrQ[4];
    loadB(0, 0, bfrP);          // prologue: first half of iter-0 B in flight
    stageA(0, Als[0]);
    __syncthreads();

    for (int kt = 0; kt < NKT; ++kt) {
        // issue second-half B for this iter (covered by stageA VALU)
        loadB(kt, 1, bfrQ);

        // stage next A tile into the other LDS buffer
        if (kt + 1 < NKT) stageA(kt + 1, Als[(kt + 1) & 1]);

        // A fragment reads (swizzled, 2-way conflict = free)
        const __bf16* Acur = Als[kt & 1];
        bf16x8 af[4];
        #pragma unroll
        for (int mt = 0; mt < 4; ++mt) {
            int row = mt * 16 + lr;
            int chunk = row * 4 + (lq ^ ((row >> 1) & 3));
            af[mt] = *(const bf16x8*)(Acur + chunk * 8);
        }

        // MFMA half 1: bfrP (issued one phase earlier)
        #pragma unroll
        for (int mt = 0; mt < 4; ++mt)
            #pragma unroll
            for (int nt = 0; nt < 4; ++nt)
                acc[mt][nt] = __builtin_amdgcn_mfma_f32_16x16x32_bf16(
                    af[mt], bfrP[nt], acc[mt][nt], 0, 0, 0);

        // issue first-half B for NEXT iter
        if (kt + 1 < NKT) loadB(kt + 1, 0, bfrP);

        // MFMA half 2: bfrQ
        #pragma unroll
        for (int mt = 0; mt < 4; ++mt)
            #pragma unroll
            for (int nt = 0; nt < 4; ++nt)
                acc[mt][nt + 4] = __builtin_amdgcn_mfma_f32_16x16x32_bf16(
                    af[mt], bfrQ[nt], acc[mt][nt + 4], 0, 0, 0);

        __syncthreads();
    }

    // ---- fused epilogue: +mod_b, LayerNorm over 512 cols, gelu, store ----
    float mbv[8], gv[8], bev[8];
    #pragma unroll
    for (int nt = 0; nt < 8; ++nt) {
        int col = wn * 128 + nt * 16 + lr;
        mbv[nt] = mod_b[col];
        gv[nt]  = mod_gamma[col];
        bev[nt] = mod_beta[col];
    }
    #pragma unroll
    for (int mt = 0; mt < 4; ++mt)
        #pragma unroll
        for (int nt = 0; nt < 8; ++nt)
            #pragma unroll
            for (int r = 0; r < 4; ++r)
                acc[mt][nt][r] += mbv[nt];

    #pragma unroll
    for (int mt = 0; mt < 4; ++mt) {
        #pragma unroll
        for (int r = 0; r < 4; ++r) {
            float s = 0.f, ss = 0.f;
            #pragma unroll
            for (int nt = 0; nt < 8; ++nt) {
                float y = acc[mt][nt][r];
                s += y;
                ss = fmaf(y, y, ss);
            }
            #pragma unroll
            for (int off = 1; off < 16; off <<= 1) {
                s  += __shfl_xor(s,  off);
                ss += __shfl_xor(ss, off);
            }
            if (lr == 0) {
                int row = mt * 16 + lq * 4 + r;
                redS[row][wn] = s;
                redQ[row][wn] = ss;
            }
        }
    }
    __syncthreads();
    if (tid < TM) {
        float s  = redS[tid][0] + redS[tid][1] + redS[tid][2] + redS[tid][3];
        float ss = redQ[tid][0] + redQ[tid][1] + redQ[tid][2] + redQ[tid][3];
        const float inv_n = 1.0f / (float)H_DIM;
        float mu  = s * inv_n;
        float var = ss * inv_n - mu * mu;
        muS[tid]  = mu;
        invS[tid] = rsqrtf(var + EPS);
    }
    __syncthreads();

    #pragma unroll
    for (int mt = 0; mt < 4; ++mt) {
        #pragma unroll
        for (int r = 0; r < 4; ++r) {
            int row = mt * 16 + lq * 4 + r;
            float mu  = muS[row];
            float inv = invS[row];
            float* op = out + (size_t)(row0 + row) * H_DIM;
            #pragma unroll
            for (int nt = 0; nt < 8; ++nt) {
                int col = wn * 128 + nt * 16 + lr;
                float t = fmaf((acc[mt][nt][r] - mu) * inv, gv[nt], bev[nt]);
                op[col] = gelu_fast(t);
            }
        }
    }
}

extern "C" void kernel_launch(void* const* d_in, const int* in_sizes, int n_in,
                              void* d_out, int out_size, void* d_ws, size_t ws_size,
                              hipStream_t stream) {
    const float* x         = (const float*)d_in[0];
    const float* enc_w     = (const float*)d_in[1];
    const float* enc_b     = (const float*)d_in[2];
    const float* enc_gamma = (const float*)d_in[3];
    const float* enc_beta  = (const float*)d_in[4];
    const float* mod_w     = (const float*)d_in[5];
    const float* mod_b     = (const float*)d_in[6];
    const float* mod_gamma = (const float*)d_in[7];
    const float* mod_beta  = (const float*)d_in[8];
    float* out = (float*)d_out;

    const size_t wb_bytes = (size_t)H_DIM * K_DIM * sizeof(__bf16);  // 4 MB
    int use_ws = (ws_size >= wb_bytes) ? 1 : 0;
    __bf16* Wb = (__bf16*)d_ws;

    if (use_ws) {
        conv_w_kernel<<<(H_DIM * K_DIM) / (256 * 8), 256, 0, stream>>>(mod_w, Wb);
        fused_gemm_kernel<1><<<BS / TM, 256, 0, stream>>>(
            x, enc_w, enc_b, enc_gamma, enc_beta, mod_w, Wb,
            mod_b, mod_gamma, mod_beta, out);
    } else {
        fused_gemm_kernel<0><<<BS / TM, 256, 0, stream>>>(
            x, enc_w, enc_b, enc_gamma, enc_beta, mod_w, Wb,
            mod_b, mod_gamma, mod_beta, out);
    }
}

// Round 6
// 249.902 us; speedup vs baseline: 1.7922x; 1.1123x over previous
//
#include <hip/hip_runtime.h>
#include <hip/hip_bf16.h>
#include <math.h>

#define C_CH 8
#define H_DIM 512
#define BS 32768            // B*S
#define K_DIM 4096          // C*H
#define EPS 1e-5f

#define TM 64
#define TK 32
#define NKT (K_DIM / TK)    // 128 K-tiles

typedef __bf16 bf16x8 __attribute__((ext_vector_type(8)));
typedef __bf16 bf16x4 __attribute__((ext_vector_type(4)));
typedef float  floatx4 __attribute__((ext_vector_type(4)));

// tanh-form GELU via hw exp + rcp; max abs dev from exact erf-gelu ~3e-4.
__device__ __forceinline__ float gelu_fast(float v) {
    float x = v * fmaf(v * v, 0.07135481627f, 1.595769122f);
    float e = __expf(-x);
    return v * __builtin_amdgcn_rcpf(1.0f + e);
}

// mod_w fp32 [512][4096] -> bf16 workspace in MFMA B-fragment chunk layout:
// chunk(kt 0..127, ntile 0..31) of 64 lanes x 16B; lane l holds
// B[col = ntile*16 + (l&15)][k = kt*32 + (l>>4)*8 + i], i=0..7.
__global__ __launch_bounds__(256) void conv_w_kernel(const float* __restrict__ w,
                                                     __bf16* __restrict__ o) {
    int gtid  = blockIdx.x * 256 + threadIdx.x;   // 0..262143
    int lane  = gtid & 63;
    int chunk = gtid >> 6;                        // 0..4095
    int kt    = chunk >> 5;
    int ntile = chunk & 31;
    int col   = ntile * 16 + (lane & 15);
    int k     = kt * 32 + (lane >> 4) * 8;
    const float* src = w + (size_t)col * K_DIM + k;
    float4 a = *(const float4*)src;
    float4 b = *(const float4*)(src + 4);
    bf16x8 h;
    h[0] = (__bf16)a.x; h[1] = (__bf16)a.y; h[2] = (__bf16)a.z; h[3] = (__bf16)a.w;
    h[4] = (__bf16)b.x; h[5] = (__bf16)b.y; h[6] = (__bf16)b.z; h[7] = (__bf16)b.w;
    *(bf16x8*)(o + (size_t)gtid * 8) = h;
}

// Fused: analytic enc-LN -> gelu -> GEMM(mod_w^T) -> +mod_b -> LayerNorm -> gelu.
// 512 threads / 8 waves, wave-tile 64x64 -> acc only 64 regs/wave so
// launch_bounds(512,4) fits 4 waves/SIMD (16 waves/CU from 2 blocks).
template <int USE_WS>
__global__ __launch_bounds__(512, 4) void fused_gemm_kernel(
    const float* __restrict__ x,
    const float* __restrict__ enc_w,
    const float* __restrict__ enc_b,
    const float* __restrict__ enc_gamma,
    const float* __restrict__ enc_beta,
    const float* __restrict__ mod_w,      // fp32 fallback
    const __bf16* __restrict__ Wb,        // bf16 frag-layout (workspace)
    const float* __restrict__ mod_b,
    const float* __restrict__ mod_gamma,
    const float* __restrict__ mod_beta,
    float* __restrict__ out)
{
    __shared__ float stats[C_CH][5];
    __shared__ float pS[C_CH][TM];
    __shared__ float qS[C_CH][TM];
    __shared__ float rS[C_CH][TM];
    __shared__ __align__(16) __bf16 Als[2][TM * TK];   // 2 x 4 KB, swizzled chunks
    __shared__ float redS[TM][8];
    __shared__ float redQ[TM][8];
    __shared__ float muS[TM];
    __shared__ float invS[TM];

    const int tid  = threadIdx.x;
    const int wave = tid >> 6;        // 0..7
    const int lane = tid & 63;

    // ---- per-channel encoder stats (closed-form LN of affine map) ----
    {
        const int c = wave;
        float sw = 0.f, sb = 0.f, sww = 0.f, sbb = 0.f, swb = 0.f;
        for (int j = lane; j < H_DIM; j += 64) {
            float w = enc_w[c * H_DIM + j];
            float b = enc_b[c * H_DIM + j];
            sw += w; sb += b;
            sww = fmaf(w, w, sww);
            sbb = fmaf(b, b, sbb);
            swb = fmaf(w, b, swb);
        }
        #pragma unroll
        for (int off = 32; off; off >>= 1) {
            sw  += __shfl_xor(sw,  off);
            sb  += __shfl_xor(sb,  off);
            sww += __shfl_xor(sww, off);
            sbb += __shfl_xor(sbb, off);
            swb += __shfl_xor(swb, off);
        }
        if (lane == 0) {
            const float inv = 1.0f / (float)H_DIM;
            float mw = sw * inv, mb = sb * inv;
            stats[c][0] = mw;
            stats[c][1] = mb;
            stats[c][2] = sww * inv - mw * mw;
            stats[c][3] = sbb * inv - mb * mb;
            stats[c][4] = swb * inv - mw * mb;
        }
    }
    __syncthreads();

    // ---- per-(channel,row) p,q,r : 512 threads == 8 channels x 64 rows ----
    const int row0 = blockIdx.x * TM;
    {
        int c = wave;
        int m = lane;
        float xv = x[c * BS + row0 + m];
        float mw = stats[c][0], mb = stats[c][1];
        float vw = stats[c][2], vb = stats[c][3], cwb = stats[c][4];
        float var = fmaf(xv, fmaf(xv, vw, 2.0f * cwb), vb);
        float q = rsqrtf(var + EPS);
        float p = xv * q;
        pS[c][m] = p;
        qS[c][m] = q;
        rS[c][m] = -fmaf(p, mw, q * mb);
    }
    __syncthreads();

    const int wn = wave;             // wave tile: 64 rows x 64 cols
    const int lr = lane & 15;
    const int lq = lane >> 4;

    // stageA decomposition: tid = row*8 + kq*2 + half (4 elems / 8B per thread)
    const int arow  = tid >> 3;      // 0..63
    const int akq   = (tid >> 1) & 3;
    const int ahalf = tid & 1;
    const int wchunk = arow * 4 + (akq ^ ((arow >> 1) & 3));   // XOR bank swizzle

    floatx4 acc[4][4];
    #pragma unroll
    for (int i = 0; i < 4; ++i)
        #pragma unroll
        for (int j = 0; j < 4; ++j)
            acc[i][j] = (floatx4){0.f, 0.f, 0.f, 0.f};

    // ---- A-stage: gelu(enc-LN) for tile ktn, one 8B half-chunk per thread ----
    auto stageA = [&](int ktn, __bf16* dst) {
        const int k0 = ktn * TK;
        const int c  = k0 >> 9;
        const int j0 = c * H_DIM + (k0 & (H_DIM - 1)) + akq * 8 + ahalf * 4;
        float p = pS[c][arow], q = qS[c][arow], r = rS[c][arow];
        float4 w = *(const float4*)(enc_w + j0);
        float4 b = *(const float4*)(enc_b + j0);
        float4 g = *(const float4*)(enc_gamma + j0);
        float4 e = *(const float4*)(enc_beta + j0);
        float fw[4] = {w.x, w.y, w.z, w.w};
        float fb[4] = {b.x, b.y, b.z, b.w};
        float fg[4] = {g.x, g.y, g.z, g.w};
        float fe[4] = {e.x, e.y, e.z, e.w};
        bf16x4 hv;
        #pragma unroll
        for (int i = 0; i < 4; ++i) {
            float t = fmaf(p, fw[i], fmaf(q, fb[i], r));
            float v = fmaf(t, fg[i], fe[i]);
            hv[i] = (__bf16)gelu_fast(v);
        }
        *(bf16x4*)(dst + wchunk * 8 + ahalf * 4) = hv;
    };

    // ---- B-frag loader: 2 frags (one n-half of the wave's 64 cols) ----
    auto loadB = [&](int ktn, int half, bf16x8* dst) {
        if (USE_WS) {
            const __bf16* base = Wb + ((size_t)(ktn * 32 + wn * 4 + half * 2) * 64 + lane) * 8;
            dst[0] = *(const bf16x8*)(base);
            dst[1] = *(const bf16x8*)(base + 512);
        } else {
            const int kk = ktn * 32 + lq * 8;
            #pragma unroll
            for (int nt = 0; nt < 2; ++nt) {
                int col = wn * 64 + (half * 2 + nt) * 16 + lr;
                const float* src = mod_w + (size_t)col * K_DIM + kk;
                float4 a = *(const float4*)src;
                float4 b = *(const float4*)(src + 4);
                bf16x8 h;
                h[0] = (__bf16)a.x; h[1] = (__bf16)a.y; h[2] = (__bf16)a.z; h[3] = (__bf16)a.w;
                h[4] = (__bf16)b.x; h[5] = (__bf16)b.y; h[6] = (__bf16)b.z; h[7] = (__bf16)b.w;
                dst[nt] = h;
            }
        }
    };

    bf16x8 bfrP[2], bfrQ[2];
    loadB(0, 0, bfrP);          // prologue: first half of iter-0 B in flight
    stageA(0, Als[0]);
    __syncthreads();

    for (int kt = 0; kt < NKT; ++kt) {
        // issue second-half B for this iter (covered by stageA VALU)
        loadB(kt, 1, bfrQ);

        // stage next A tile into the other LDS buffer
        if (kt + 1 < NKT) stageA(kt + 1, Als[(kt + 1) & 1]);

        // A fragment reads (swizzled, 2-way conflict = free)
        const __bf16* Acur = Als[kt & 1];
        bf16x8 af[4];
        #pragma unroll
        for (int mt = 0; mt < 4; ++mt) {
            int row = mt * 16 + lr;
            int chunk = row * 4 + (lq ^ ((row >> 1) & 3));
            af[mt] = *(const bf16x8*)(Acur + chunk * 8);
        }

        // MFMA half 1: bfrP (issued one phase earlier)
        #pragma unroll
        for (int mt = 0; mt < 4; ++mt)
            #pragma unroll
            for (int nt = 0; nt < 2; ++nt)
                acc[mt][nt] = __builtin_amdgcn_mfma_f32_16x16x32_bf16(
                    af[mt], bfrP[nt], acc[mt][nt], 0, 0, 0);

        // issue first-half B for NEXT iter
        if (kt + 1 < NKT) loadB(kt + 1, 0, bfrP);

        // MFMA half 2: bfrQ
        #pragma unroll
        for (int mt = 0; mt < 4; ++mt)
            #pragma unroll
            for (int nt = 0; nt < 2; ++nt)
                acc[mt][nt + 2] = __builtin_amdgcn_mfma_f32_16x16x32_bf16(
                    af[mt], bfrQ[nt], acc[mt][nt + 2], 0, 0, 0);

        __syncthreads();
    }

    // ---- fused epilogue: +mod_b, LayerNorm over 512 cols, gelu, store ----
    float mbv[4], gv[4], bev[4];
    #pragma unroll
    for (int nt = 0; nt < 4; ++nt) {
        int col = wn * 64 + nt * 16 + lr;
        mbv[nt] = mod_b[col];
        gv[nt]  = mod_gamma[col];
        bev[nt] = mod_beta[col];
    }
    #pragma unroll
    for (int mt = 0; mt < 4; ++mt)
        #pragma unroll
        for (int nt = 0; nt < 4; ++nt)
            #pragma unroll
            for (int r = 0; r < 4; ++r)
                acc[mt][nt][r] += mbv[nt];

    // per-row partial sums within this wave's 64 cols
    #pragma unroll
    for (int mt = 0; mt < 4; ++mt) {
        #pragma unroll
        for (int r = 0; r < 4; ++r) {
            float s = 0.f, ss = 0.f;
            #pragma unroll
            for (int nt = 0; nt < 4; ++nt) {
                float y = acc[mt][nt][r];
                s += y;
                ss = fmaf(y, y, ss);
            }
            #pragma unroll
            for (int off = 1; off < 16; off <<= 1) {
                s  += __shfl_xor(s,  off);
                ss += __shfl_xor(ss, off);
            }
            if (lr == 0) {
                int row = mt * 16 + lq * 4 + r;
                redS[row][wn] = s;
                redQ[row][wn] = ss;
            }
        }
    }
    __syncthreads();
    if (tid < TM) {
        float s = 0.f, ss = 0.f;
        #pragma unroll
        for (int w = 0; w < 8; ++w) {
            s  += redS[tid][w];
            ss += redQ[tid][w];
        }
        const float inv_n = 1.0f / (float)H_DIM;
        float mu  = s * inv_n;
        float var = ss * inv_n - mu * mu;
        muS[tid]  = mu;
        invS[tid] = rsqrtf(var + EPS);
    }
    __syncthreads();

    #pragma unroll
    for (int mt = 0; mt < 4; ++mt) {
        #pragma unroll
        for (int r = 0; r < 4; ++r) {
            int row = mt * 16 + lq * 4 + r;
            float mu  = muS[row];
            float inv = invS[row];
            float* op = out + (size_t)(row0 + row) * H_DIM;
            #pragma unroll
            for (int nt = 0; nt < 4; ++nt) {
                int col = wn * 64 + nt * 16 + lr;
                float t = fmaf((acc[mt][nt][r] - mu) * inv, gv[nt], bev[nt]);
                op[col] = gelu_fast(t);
            }
        }
    }
}

extern "C" void kernel_launch(void* const* d_in, const int* in_sizes, int n_in,
                              void* d_out, int out_size, void* d_ws, size_t ws_size,
                              hipStream_t stream) {
    const float* x         = (const float*)d_in[0];
    const float* enc_w     = (const float*)d_in[1];
    const float* enc_b     = (const float*)d_in[2];
    const float* enc_gamma = (const float*)d_in[3];
    const float* enc_beta  = (const float*)d_in[4];
    const float* mod_w     = (const float*)d_in[5];
    const float* mod_b     = (const float*)d_in[6];
    const float* mod_gamma = (const float*)d_in[7];
    const float* mod_beta  = (const float*)d_in[8];
    float* out = (float*)d_out;

    const size_t wb_bytes = (size_t)H_DIM * K_DIM * sizeof(__bf16);  // 4 MB
    int use_ws = (ws_size >= wb_bytes) ? 1 : 0;
    __bf16* Wb = (__bf16*)d_ws;

    if (use_ws) {
        conv_w_kernel<<<(H_DIM * K_DIM) / (256 * 8), 256, 0, stream>>>(mod_w, Wb);
        fused_gemm_kernel<1><<<BS / TM, 512, 0, stream>>>(
            x, enc_w, enc_b, enc_gamma, enc_beta, mod_w, Wb,
            mod_b, mod_gamma, mod_beta, out);
    } else {
        fused_gemm_kernel<0><<<BS / TM, 512, 0, stream>>>(
            x, enc_w, enc_b, enc_gamma, enc_beta, mod_w, Wb,
            mod_b, mod_gamma, mod_beta, out);
    }
}

// Round 7
// 249.806 us; speedup vs baseline: 1.7929x; 1.0004x over previous
//
#include <hip/hip_runtime.h>
#include <hip/hip_bf16.h>
#include <math.h>

#define C_CH 8
#define H_DIM 512
#define BS 32768            // B*S
#define K_DIM 4096          // C*H
#define EPS 1e-5f

#define TM 64
#define TK 32
#define NKT (K_DIM / TK)    // 128 K-tiles, processed in 32 groups of 4

typedef __bf16 bf16x8 __attribute__((ext_vector_type(8)));
typedef __bf16 bf16x4 __attribute__((ext_vector_type(4)));
typedef float  floatx4 __attribute__((ext_vector_type(4)));

// tanh-form GELU, exp2-folded: gelu(v) ~= v * sigmoid(1.5957691*(v+0.044715 v^3))
// constants pre-multiplied by log2(e); max abs dev from exact erf-gelu ~3e-4.
__device__ __forceinline__ float gelu_fast(float v) {
    float x2 = v * fmaf(v * v, 0.102943215f, 2.30220815f);   // x*log2e
    float e = __builtin_amdgcn_exp2f(-x2);
    return v * __builtin_amdgcn_rcpf(1.0f + e);
}

// mod_w fp32 [512][4096] -> bf16 workspace in MFMA B-fragment chunk layout:
// chunk(kt 0..127, ntile 0..31) of 64 lanes x 16B; lane l holds
// B[col = ntile*16 + (l&15)][k = kt*32 + (l>>4)*8 + i], i=0..7.
__global__ __launch_bounds__(256) void conv_w_kernel(const float* __restrict__ w,
                                                     __bf16* __restrict__ o) {
    int gtid  = blockIdx.x * 256 + threadIdx.x;   // 0..262143
    int lane  = gtid & 63;
    int chunk = gtid >> 6;                        // 0..4095
    int kt    = chunk >> 5;
    int ntile = chunk & 31;
    int col   = ntile * 16 + (lane & 15);
    int k     = kt * 32 + (lane >> 4) * 8;
    const float* src = w + (size_t)col * K_DIM + k;
    float4 a = *(const float4*)src;
    float4 b = *(const float4*)(src + 4);
    bf16x8 h;
    h[0] = (__bf16)a.x; h[1] = (__bf16)a.y; h[2] = (__bf16)a.z; h[3] = (__bf16)a.w;
    h[4] = (__bf16)b.x; h[5] = (__bf16)b.y; h[6] = (__bf16)b.z; h[7] = (__bf16)b.w;
    *(bf16x8*)(o + (size_t)gtid * 8) = h;
}

// Fused: analytic enc-LN -> gelu -> GEMM(mod_w^T) -> +mod_b -> LayerNorm -> gelu.
// 512 threads / 8 waves, wave-tile 64x64. One barrier per 4 K-tiles: A staged
// into 2 groups x 4 sub-tile LDS buffers; stageA(group g+1) interleaved with
// MFMA(group g). B frags stream global(L2)->VGPR with P/Q rotation.
template <int USE_WS>
__global__ __launch_bounds__(512, 4) void fused_gemm_kernel(
    const float* __restrict__ x,
    const float* __restrict__ enc_w,
    const float* __restrict__ enc_b,
    const float* __restrict__ enc_gamma,
    const float* __restrict__ enc_beta,
    const float* __restrict__ mod_w,      // fp32 fallback
    const __bf16* __restrict__ Wb,        // bf16 frag-layout (workspace)
    const float* __restrict__ mod_b,
    const float* __restrict__ mod_gamma,
    const float* __restrict__ mod_beta,
    float* __restrict__ out)
{
    __shared__ float stats[C_CH][5];
    __shared__ float pS[C_CH][TM];
    __shared__ float qS[C_CH][TM];
    __shared__ float rS[C_CH][TM];
    __shared__ __align__(16) __bf16 Als[2 * 4 * TM * TK];   // 32 KB, swizzled chunks
    __shared__ float redS[TM][8];
    __shared__ float redQ[TM][8];
    __shared__ float muS[TM];
    __shared__ float invS[TM];

    const int tid  = threadIdx.x;
    const int wave = tid >> 6;        // 0..7
    const int lane = tid & 63;

    // ---- per-channel encoder stats (closed-form LN of affine map) ----
    {
        const int c = wave;
        float sw = 0.f, sb = 0.f, sww = 0.f, sbb = 0.f, swb = 0.f;
        for (int j = lane; j < H_DIM; j += 64) {
            float w = enc_w[c * H_DIM + j];
            float b = enc_b[c * H_DIM + j];
            sw += w; sb += b;
            sww = fmaf(w, w, sww);
            sbb = fmaf(b, b, sbb);
            swb = fmaf(w, b, swb);
        }
        #pragma unroll
        for (int off = 32; off; off >>= 1) {
            sw  += __shfl_xor(sw,  off);
            sb  += __shfl_xor(sb,  off);
            sww += __shfl_xor(sww, off);
            sbb += __shfl_xor(sbb, off);
            swb += __shfl_xor(swb, off);
        }
        if (lane == 0) {
            const float inv = 1.0f / (float)H_DIM;
            float mw = sw * inv, mb = sb * inv;
            stats[c][0] = mw;
            stats[c][1] = mb;
            stats[c][2] = sww * inv - mw * mw;
            stats[c][3] = sbb * inv - mb * mb;
            stats[c][4] = swb * inv - mw * mb;
        }
    }
    __syncthreads();

    // ---- per-(channel,row) p,q,r : 512 threads == 8 channels x 64 rows ----
    const int row0 = blockIdx.x * TM;
    {
        int c = wave;
        int m = lane;
        float xv = x[c * BS + row0 + m];
        float mw = stats[c][0], mb = stats[c][1];
        float vw = stats[c][2], vb = stats[c][3], cwb = stats[c][4];
        float var = fmaf(xv, fmaf(xv, vw, 2.0f * cwb), vb);
        float q = rsqrtf(var + EPS);
        float p = xv * q;
        pS[c][m] = p;
        qS[c][m] = q;
        rS[c][m] = -fmaf(p, mw, q * mb);
    }
    __syncthreads();

    const int wn = wave;             // wave tile: 64 rows x 64 cols
    const int lr = lane & 15;
    const int lq = lane >> 4;

    // stageA decomposition: tid = row*8 + kq*2 + half (4 elems / 8B per thread)
    const int arow  = tid >> 3;      // 0..63
    const int akq   = (tid >> 1) & 3;
    const int ahalf = tid & 1;
    const int wchunk = arow * 4 + (akq ^ ((arow >> 1) & 3));   // XOR bank swizzle

    floatx4 acc[4][4];
    #pragma unroll
    for (int i = 0; i < 4; ++i)
        #pragma unroll
        for (int j = 0; j < 4; ++j)
            acc[i][j] = (floatx4){0.f, 0.f, 0.f, 0.f};

    // ---- A-stage: gelu(enc-LN) for tile ktn, one 8B half-chunk per thread ----
    auto stageA = [&](int ktn, __bf16* dst) {
        const int k0 = ktn * TK;
        const int c  = k0 >> 9;
        const int j0 = c * H_DIM + (k0 & (H_DIM - 1)) + akq * 8 + ahalf * 4;
        float p = pS[c][arow], q = qS[c][arow], r = rS[c][arow];
        float4 w = *(const float4*)(enc_w + j0);
        float4 b = *(const float4*)(enc_b + j0);
        float4 g = *(const float4*)(enc_gamma + j0);
        float4 e = *(const float4*)(enc_beta + j0);
        float fw[4] = {w.x, w.y, w.z, w.w};
        float fb[4] = {b.x, b.y, b.z, b.w};
        float fg[4] = {g.x, g.y, g.z, g.w};
        float fe[4] = {e.x, e.y, e.z, e.w};
        bf16x4 hv;
        #pragma unroll
        for (int i = 0; i < 4; ++i) {
            float t = fmaf(p, fw[i], fmaf(q, fb[i], r));
            float v = fmaf(t, fg[i], fe[i]);
            hv[i] = (__bf16)gelu_fast(v);
        }
        *(bf16x4*)(dst + wchunk * 8 + ahalf * 4) = hv;
    };

    // ---- B-frag loader: 2 frags (one n-half of the wave's 64 cols) ----
    auto loadB = [&](int ktn, int half, bf16x8* dst) {
        if (USE_WS) {
            const __bf16* base = Wb + ((size_t)(ktn * 32 + wn * 4 + half * 2) * 64 + lane) * 8;
            dst[0] = *(const bf16x8*)(base);
            dst[1] = *(const bf16x8*)(base + 512);
        } else {
            const int kk = ktn * 32 + lq * 8;
            #pragma unroll
            for (int nt = 0; nt < 2; ++nt) {
                int col = wn * 64 + (half * 2 + nt) * 16 + lr;
                const float* src = mod_w + (size_t)col * K_DIM + kk;
                float4 a = *(const float4*)src;
                float4 b = *(const float4*)(src + 4);
                bf16x8 h;
                h[0] = (__bf16)a.x; h[1] = (__bf16)a.y; h[2] = (__bf16)a.z; h[3] = (__bf16)a.w;
                h[4] = (__bf16)b.x; h[5] = (__bf16)b.y; h[6] = (__bf16)b.z; h[7] = (__bf16)b.w;
                dst[nt] = h;
            }
        }
    };

    bf16x8 bfrP[2], bfrQ[2];
    loadB(0, 0, bfrP);          // prologue: first half of k-tile-0 B in flight
    #pragma unroll
    for (int sub = 0; sub < 4; ++sub)
        stageA(sub, Als + sub * (TM * TK));
    __syncthreads();

    for (int g = 0; g < NKT / 4; ++g) {
        const __bf16* cur = Als + (g & 1) * (4 * TM * TK);
        __bf16*       nxt = Als + ((g + 1) & 1) * (4 * TM * TK);

        #pragma unroll
        for (int sub = 0; sub < 4; ++sub) {
            const int kt = g * 4 + sub;

            // second-half B for this k-tile (covered by stageA VALU below)
            loadB(kt, 1, bfrQ);

            // stage one sub-tile of the NEXT group's A
            if (g + 1 < NKT / 4) stageA(kt + 4, nxt + sub * (TM * TK));

            // A fragment reads (swizzled, 2-way conflict = free)
            const __bf16* Acur = cur + sub * (TM * TK);
            bf16x8 af[4];
            #pragma unroll
            for (int mt = 0; mt < 4; ++mt) {
                int row = mt * 16 + lr;
                int chunk = row * 4 + (lq ^ ((row >> 1) & 3));
                af[mt] = *(const bf16x8*)(Acur + chunk * 8);
            }

            // MFMA half 1: bfrP (issued one phase earlier)
            #pragma unroll
            for (int mt = 0; mt < 4; ++mt)
                #pragma unroll
                for (int nt = 0; nt < 2; ++nt)
                    acc[mt][nt] = __builtin_amdgcn_mfma_f32_16x16x32_bf16(
                        af[mt], bfrP[nt], acc[mt][nt], 0, 0, 0);

            // first-half B for the NEXT k-tile
            if (kt + 1 < NKT) loadB(kt + 1, 0, bfrP);

            // MFMA half 2: bfrQ
            #pragma unroll
            for (int mt = 0; mt < 4; ++mt)
                #pragma unroll
                for (int nt = 0; nt < 2; ++nt)
                    acc[mt][nt + 2] = __builtin_amdgcn_mfma_f32_16x16x32_bf16(
                        af[mt], bfrQ[nt], acc[mt][nt + 2], 0, 0, 0);
        }
        __syncthreads();      // one barrier per 4 k-tiles
    }

    // ---- fused epilogue: +mod_b, LayerNorm over 512 cols, gelu, store ----
    float mbv[4], gv[4], bev[4];
    #pragma unroll
    for (int nt = 0; nt < 4; ++nt) {
        int col = wn * 64 + nt * 16 + lr;
        mbv[nt] = mod_b[col];
        gv[nt]  = mod_gamma[col];
        bev[nt] = mod_beta[col];
    }
    #pragma unroll
    for (int mt = 0; mt < 4; ++mt)
        #pragma unroll
        for (int nt = 0; nt < 4; ++nt)
            #pragma unroll
            for (int r = 0; r < 4; ++r)
                acc[mt][nt][r] += mbv[nt];

    // per-row partial sums within this wave's 64 cols
    #pragma unroll
    for (int mt = 0; mt < 4; ++mt) {
        #pragma unroll
        for (int r = 0; r < 4; ++r) {
            float s = 0.f, ss = 0.f;
            #pragma unroll
            for (int nt = 0; nt < 4; ++nt) {
                float y = acc[mt][nt][r];
                s += y;
                ss = fmaf(y, y, ss);
            }
            #pragma unroll
            for (int off = 1; off < 16; off <<= 1) {
                s  += __shfl_xor(s,  off);
                ss += __shfl_xor(ss, off);
            }
            if (lr == 0) {
                int row = mt * 16 + lq * 4 + r;
                redS[row][wn] = s;
                redQ[row][wn] = ss;
            }
        }
    }
    __syncthreads();
    if (tid < TM) {
        float s = 0.f, ss = 0.f;
        #pragma unroll
        for (int w = 0; w < 8; ++w) {
            s  += redS[tid][w];
            ss += redQ[tid][w];
        }
        const float inv_n = 1.0f / (float)H_DIM;
        float mu  = s * inv_n;
        float var = ss * inv_n - mu * mu;
        muS[tid]  = mu;
        invS[tid] = rsqrtf(var + EPS);
    }
    __syncthreads();

    #pragma unroll
    for (int mt = 0; mt < 4; ++mt) {
        #pragma unroll
        for (int r = 0; r < 4; ++r) {
            int row = mt * 16 + lq * 4 + r;
            float mu  = muS[row];
            float inv = invS[row];
            float* op = out + (size_t)(row0 + row) * H_DIM;
            #pragma unroll
            for (int nt = 0; nt < 4; ++nt) {
                int col = wn * 64 + nt * 16 + lr;
                float t = fmaf((acc[mt][nt][r] - mu) * inv, gv[nt], bev[nt]);
                op[col] = gelu_fast(t);
            }
        }
    }
}

extern "C" void kernel_launch(void* const* d_in, const int* in_sizes, int n_in,
                              void* d_out, int out_size, void* d_ws, size_t ws_size,
                              hipStream_t stream) {
    const float* x         = (const float*)d_in[0];
    const float* enc_w     = (const float*)d_in[1];
    const float* enc_b     = (const float*)d_in[2];
    const float* enc_gamma = (const float*)d_in[3];
    const float* enc_beta  = (const float*)d_in[4];
    const float* mod_w     = (const float*)d_in[5];
    const float* mod_b     = (const float*)d_in[6];
    const float* mod_gamma = (const float*)d_in[7];
    const float* mod_beta  = (const float*)d_in[8];
    float* out = (float*)d_out;

    const size_t wb_bytes = (size_t)H_DIM * K_DIM * sizeof(__bf16);  // 4 MB
    int use_ws = (ws_size >= wb_bytes) ? 1 : 0;
    __bf16* Wb = (__bf16*)d_ws;

    if (use_ws) {
        conv_w_kernel<<<(H_DIM * K_DIM) / (256 * 8), 256, 0, stream>>>(mod_w, Wb);
        fused_gemm_kernel<1><<<BS / TM, 512, 0, stream>>>(
            x, enc_w, enc_b, enc_gamma, enc_beta, mod_w, Wb,
            mod_b, mod_gamma, mod_beta, out);
    } else {
        fused_gemm_kernel<0><<<BS / TM, 512, 0, stream>>>(
            x, enc_w, enc_b, enc_gamma, enc_beta, mod_w, Wb,
            mod_b, mod_gamma, mod_beta, out);
    }
}